// Round 1
// baseline (7515.488 us; speedup 1.0000x reference)
//
#include <hip/hip_runtime.h>
#include <hip/hip_bf16.h>
#include <stdint.h>

// LSTM: B=64, S=512, I=1024, H=1024, gates G=4096.
// Phase 1: x_proj[s*B+b][g] = sum_k x[b,s,k]*W_ih[g,k] + b_ih[g] + b_hh[g]  (bf16 MFMA GEMM)
// Phase 2: 512 sequential step kernels: gates = x_proj[t] + h@W_hh^T, LSTM cell fused.
// h ping-pongs between two bf16 buffers (cross-block race avoidance).

#define B_ 64
#define S_ 512
#define K_ 1024
#define G_ 4096

typedef float f32x4 __attribute__((ext_vector_type(4)));
typedef __bf16 bf16x8 __attribute__((ext_vector_type(8)));

__device__ __forceinline__ uint16_t f2bf(float f) {
  union { float f; uint32_t u; } v; v.f = f;
  uint32_t u = v.u;
  u += 0x7fffu + ((u >> 16) & 1u);   // round-to-nearest-even
  return (uint16_t)(u >> 16);
}
__device__ __forceinline__ float bf2f(uint16_t h) {
  union { uint32_t u; float f; } v; v.u = ((uint32_t)h) << 16;
  return v.f;
}
__device__ __forceinline__ float sigm(float x) { return 1.0f / (1.0f + __expf(-x)); }
__device__ __forceinline__ float tanh_f(float x) { return 1.0f - 2.0f / (1.0f + __expf(2.0f * x)); }

__device__ __forceinline__ void gload_lds16(const void* g, void* lds) {
  __builtin_amdgcn_global_load_lds(
      (const __attribute__((address_space(1))) void*)g,
      (__attribute__((address_space(3))) void*)lds, 16, 0, 0);
}

// ---------------- f32 -> bf16 convert (8 elems/thread) ----------------
__global__ void k_cvt(const float* __restrict__ src, uint16_t* __restrict__ dst, int n8) {
  int i = blockIdx.x * 256 + threadIdx.x;
  if (i >= n8) return;
  const f32x4* s = (const f32x4*)src + (size_t)i * 2;
  f32x4 a = s[0], b = s[1];
  union { uint16_t u[8]; uint4 v; } o;
  o.u[0] = f2bf(a[0]); o.u[1] = f2bf(a[1]); o.u[2] = f2bf(a[2]); o.u[3] = f2bf(a[3]);
  o.u[4] = f2bf(b[0]); o.u[5] = f2bf(b[1]); o.u[6] = f2bf(b[2]); o.u[7] = f2bf(b[3]);
  *((uint4*)dst + i) = o.v;
}

// ---------------- init h (bf16) and c (f32) from h0/c0 ----------------
__global__ void k_init(const float* __restrict__ h0, const float* __restrict__ c0,
                       uint16_t* __restrict__ hbf, float* __restrict__ c, int n) {
  int i = blockIdx.x * 256 + threadIdx.x;
  if (i >= n) return;
  hbf[i] = f2bf(h0[i]);
  c[i] = c0[i];
}

// ---------------- Phase 1 GEMM: 128x128 tile, BK=64, 4 waves ----------------
// A = xbf [32768][1024] (row m = b*512+s), W = wih [4096][1024], out row = s*64+b.
__global__ __launch_bounds__(256) void k_gemm1(
    const uint16_t* __restrict__ A, const uint16_t* __restrict__ W,
    const float* __restrict__ bih, const float* __restrict__ bhh,
    uint16_t* __restrict__ xproj) {
  __shared__ char lds[32768];           // A tile [128][64] bf16 | B tile [128][64] bf16 (XOR-swizzled)
  const int tid = threadIdx.x;
  const int w = tid >> 6, l = tid & 63;

  // XCD-contiguous swizzle (8192 blocks, 8 XCDs, bijective since 8192%8==0)
  int orig = blockIdx.x;
  int wg = (orig & 7) * 1024 + (orig >> 3);
  const int tm = wg >> 5;   // 0..255 (M tiles)
  const int tn = wg & 31;   // 0..31  (N tiles)
  const int wrow = w >> 1, wcol = w & 1;

  f32x4 acc[4][4] = {};

  for (int kt = 0; kt < 16; ++kt) {
    const int k0 = kt * 64;
    __syncthreads();
    // stage A and B tiles: linear LDS dest, inverse-swizzled global source (rule #21)
#pragma unroll
    for (int it = 0; it < 4; ++it) {
      int o = (it * 256 + tid) * 16;
      int row = o >> 7;
      int colb = (o & 127) ^ ((row & 7) << 4);
      gload_lds16((const char*)A + ((size_t)(tm * 128 + row) * 2048 + k0 * 2 + colb),
                  lds + (it * 256 + (w << 6)) * 16);
    }
#pragma unroll
    for (int it = 0; it < 4; ++it) {
      int o = (it * 256 + tid) * 16;
      int row = o >> 7;
      int colb = (o & 127) ^ ((row & 7) << 4);
      gload_lds16((const char*)W + ((size_t)(tn * 128 + row) * 2048 + k0 * 2 + colb),
                  lds + 16384 + (it * 256 + (w << 6)) * 16);
    }
    __syncthreads();
#pragma unroll
    for (int kk = 0; kk < 64; kk += 32) {
      const int kb = (kk + ((l >> 4) << 3)) * 2;
      bf16x8 af[4], bfr[4];
#pragma unroll
      for (int fr = 0; fr < 4; ++fr) {
        int r = (wrow << 6) + (fr << 4) + (l & 15);
        af[fr] = *(const bf16x8*)(lds + r * 128 + (kb ^ ((r & 7) << 4)));
      }
#pragma unroll
      for (int fc = 0; fc < 4; ++fc) {
        int r = (wcol << 6) + (fc << 4) + (l & 15);
        bfr[fc] = *(const bf16x8*)(lds + 16384 + r * 128 + (kb ^ ((r & 7) << 4)));
      }
#pragma unroll
      for (int fr = 0; fr < 4; ++fr)
#pragma unroll
        for (int fc = 0; fc < 4; ++fc)
          acc[fr][fc] = __builtin_amdgcn_mfma_f32_16x16x32_bf16(af[fr], bfr[fc], acc[fr][fc], 0, 0, 0);
    }
  }
  // epilogue: bias add, bf16 store, row permutation (b*512+s) -> (s*64+b)
#pragma unroll
  for (int fc = 0; fc < 4; ++fc) {
    int n = tn * 128 + (wcol << 6) + (fc << 4) + (l & 15);
    float bias = bih[n] + bhh[n];
#pragma unroll
    for (int fr = 0; fr < 4; ++fr) {
#pragma unroll
      for (int j = 0; j < 4; ++j) {
        int m = tm * 128 + (wrow << 6) + (fr << 4) + ((l >> 4) << 2) + j;
        int b = m >> 9, s = m & 511;
        xproj[(size_t)(s * 64 + b) * G_ + n] = f2bf(acc[fr][fc][j] + bias);
      }
    }
  }
}

// ---------------- Phase 2 step: gates GEMM + LSTM cell ----------------
// 64 blocks x 256 thr. Block owns 16 h-cols; wave w owns gate w.
// A = hin [64][1024] bf16 staged in LDS (swizzled, double-buffered); B = W_hh rows direct from L2.
__global__ __launch_bounds__(256) void k_step(
    const uint16_t* __restrict__ xproj_t,   // [64][4096]
    const uint16_t* __restrict__ whh,       // [4096][1024]
    const uint16_t* __restrict__ hin,       // [64][1024]
    uint16_t* __restrict__ hout,
    float* __restrict__ c,                  // [64][1024]
    float* __restrict__ out_t) {            // [64][1024]
  __shared__ char lds[16384];               // 2x 8KB h-staging; reused as [4][64][16] f32 gates
  const int tid = threadIdx.x;
  const int w = tid >> 6, l = tid & 63;
  const int hc0 = blockIdx.x * 16;

  f32x4 acc[4] = {};

  // prologue: stage k-tile 0 into buf0
#pragma unroll
  for (int it = 0; it < 2; ++it) {
    int o = (it * 256 + tid) * 16;
    int row = o >> 7;
    int colb = (o & 127) ^ ((row & 7) << 4);
    gload_lds16((const char*)hin + ((size_t)row * 2048 + colb),
                lds + (it * 256 + (w << 6)) * 16);
  }
  int cur = 0;
  for (int kt = 0; kt < 16; ++kt) {
    const int k0 = kt * 64;
    __syncthreads();   // drains vmcnt -> buf[cur] ready; also protects buf[cur^1] from overwrite
    if (kt < 15) {
      const int k1 = k0 + 64;
#pragma unroll
      for (int it = 0; it < 2; ++it) {
        int o = (it * 256 + tid) * 16;
        int row = o >> 7;
        int colb = (o & 127) ^ ((row & 7) << 4);
        gload_lds16((const char*)hin + ((size_t)row * 2048 + k1 * 2 + colb),
                    lds + (cur ^ 1) * 8192 + (it * 256 + (w << 6)) * 16);
      }
    }
    const char* buf = lds + cur * 8192;
#pragma unroll
    for (int kk = 0; kk < 64; kk += 32) {
      const int kb = (kk + ((l >> 4) << 3)) * 2;
      bf16x8 bfrag = *(const bf16x8*)((const char*)whh +
          ((size_t)(w * 1024 + hc0 + (l & 15)) * 1024 + k0 + kk + ((l >> 4) << 3)) * 2);
#pragma unroll
      for (int fr = 0; fr < 4; ++fr) {
        int r = (fr << 4) + (l & 15);
        bf16x8 af = *(const bf16x8*)(buf + r * 128 + (kb ^ ((r & 7) << 4)));
        acc[fr] = __builtin_amdgcn_mfma_f32_16x16x32_bf16(af, bfrag, acc[fr], 0, 0, 0);
      }
    }
    cur ^= 1;
  }
  __syncthreads();
  // gate exchange: wave w -> gl[w][b][col]
  float* gl = (float*)lds;
#pragma unroll
  for (int fr = 0; fr < 4; ++fr)
#pragma unroll
    for (int j = 0; j < 4; ++j) {
      int b = (fr << 4) + ((l >> 4) << 2) + j;
      gl[(w * 64 + b) * 16 + (l & 15)] = acc[fr][j];
    }
  __syncthreads();
  // fused LSTM cell: 1024 cells/block, 4 per thread
#pragma unroll
  for (int r0 = 0; r0 < 4; ++r0) {
    int idx = r0 * 256 + tid;
    int b = idx >> 4, col = idx & 15;
    int hcol = hc0 + col;
    float gi = gl[(0 * 64 + b) * 16 + col] + bf2f(xproj_t[b * G_ + hcol]);
    float gf = gl[(1 * 64 + b) * 16 + col] + bf2f(xproj_t[b * G_ + 1024 + hcol]);
    float gg = gl[(2 * 64 + b) * 16 + col] + bf2f(xproj_t[b * G_ + 2048 + hcol]);
    float go = gl[(3 * 64 + b) * 16 + col] + bf2f(xproj_t[b * G_ + 3072 + hcol]);
    int ci = b * 1024 + hcol;
    float cn = sigm(gf) * c[ci] + sigm(gi) * tanh_f(gg);
    float hn = sigm(go) * tanh_f(cn);
    c[ci] = cn;
    out_t[ci] = hn;
    hout[ci] = f2bf(hn);
  }
}

// ---------------- finalize: hT (copy of step-511 h) and cT ----------------
__global__ void k_final(const float* __restrict__ outbase, const float* __restrict__ c,
                        float* __restrict__ dst) {
  int i = blockIdx.x * 256 + threadIdx.x;   // 0..131071
  if (i < 65536) dst[i] = outbase[(size_t)511 * 65536 + i];
  else           dst[i] = c[i - 65536];
}

extern "C" void kernel_launch(void* const* d_in, const int* in_sizes, int n_in,
                              void* d_out, int out_size, void* d_ws, size_t ws_size,
                              hipStream_t stream) {
  const float* x   = (const float*)d_in[0];
  const float* h0  = (const float*)d_in[1];
  const float* c0  = (const float*)d_in[2];
  const float* Wih = (const float*)d_in[3];
  const float* Whh = (const float*)d_in[4];
  const float* bih = (const float*)d_in[5];
  const float* bhh = (const float*)d_in[6];
  float* out = (float*)d_out;

  char* ws = (char*)d_ws;
  uint16_t* xbf   = (uint16_t*)(ws);                 //  67,108,864 B
  uint16_t* wihbf = (uint16_t*)(ws + 67108864);      //   8,388,608 B
  uint16_t* whhbf = (uint16_t*)(ws + 75497472);      //   8,388,608 B
  uint16_t* xproj = (uint16_t*)(ws + 83886080);      // 268,435,456 B
  uint16_t* hb0   = (uint16_t*)(ws + 352321536);     //     131,072 B
  uint16_t* hb1   = (uint16_t*)(ws + 352452608);     //     131,072 B
  float*    cbuf  = (float*)   (ws + 352583680);     //     262,144 B

  k_cvt<<<16384, 256, 0, stream>>>(x, xbf, 4194304);
  k_cvt<<<2048, 256, 0, stream>>>(Wih, wihbf, 524288);
  k_cvt<<<2048, 256, 0, stream>>>(Whh, whhbf, 524288);
  k_init<<<256, 256, 0, stream>>>(h0, c0, hb0, cbuf, 65536);
  k_gemm1<<<8192, 256, 0, stream>>>(xbf, wihbf, bih, bhh, xproj);

  uint16_t* hin = hb0;
  uint16_t* hout = hb1;
  for (int t = 0; t < 512; ++t) {
    k_step<<<64, 256, 0, stream>>>(xproj + (size_t)t * 262144, whhbf, hin, hout, cbuf,
                                   out + (size_t)t * 65536);
    uint16_t* tmp = hin; hin = hout; hout = tmp;
  }
  k_final<<<512, 256, 0, stream>>>(out, cbuf, out + 33554432);
}